// Round 3
// baseline (227.224 us; speedup 1.0000x reference)
//
#include <hip/hip_runtime.h>
#include <stdint.h>

#define NN 8192
#define CC 128
#define TT 512
#define LL 30
#define CAP 64

typedef unsigned int uint32;
typedef unsigned short u16;

typedef float f32x4 __attribute__((ext_vector_type(4)));
typedef short bf16x8 __attribute__((ext_vector_type(8)));

__device__ __forceinline__ float bf2f(uint32 h) { return __uint_as_float(h << 16); }
__device__ __forceinline__ u16 f2bf(float f) {
    uint32 u = __float_as_uint(f);
    u = (u + 0x7fffu + ((u >> 16) & 1u)) >> 16;
    return (u16)u;
}
__device__ __forceinline__ uint32 pack2(float a, float b) {
    return (uint32)f2bf(a) | ((uint32)f2bf(b) << 16);
}

// ============ k_init: adj scan + W frag pack + x0->bf16 + zero rows/coefs/counters ============
// blocks [0,2048): adj rows; [2048,2336): wfrag; [2336,3360): x0 convert; 3360: small init
__global__ __launch_bounds__(256) void k_init(
    const float* __restrict__ adj,
    const float* __restrict__ W1r, const float* __restrict__ W1s,
    const float* __restrict__ W2r, const float* __restrict__ W2s,
    const float* __restrict__ W3r, const float* __restrict__ W3s,
    const float* __restrict__ Wl, const float* __restrict__ x0,
    int* __restrict__ nbr, int* __restrict__ cnt,
    u16* __restrict__ wfrag, u16* __restrict__ x0bf,
    u16* __restrict__ yp1, u16* __restrict__ yp2, u16* __restrict__ yp3,
    float* __restrict__ coefs, uint32* __restrict__ counters) {
    int b = blockIdx.x, tid = threadIdx.x;
    if (b < 2048) {
        int row = b * 4 + (tid >> 6);
        int lane = tid & 63;
        const float4* arow = (const float4*)(adj + (size_t)row * NN);
        int base = 0;
        int* dst = nbr + (size_t)row * CAP;
        for (int it = 0; it < 32; ++it) {
            float4 v = arow[it * 64 + lane];
            float vv[4] = {v.x, v.y, v.z, v.w};
#pragma unroll
            for (int j = 0; j < 4; ++j) {
                unsigned long long m = __ballot(vv[j] != 0.f);
                if (vv[j] != 0.f) {
                    int pos = base + __popcll(m & ((1ull << lane) - 1ull));
                    if (pos < CAP) dst[pos] = it * 256 + lane * 4 + j;
                }
                base += __popcll(m);
            }
        }
        int nn = base < CAP ? base : CAP;
        int npad = (nn + 3) & ~3;
        for (int p = nn + lane; p < npad; p += 64) dst[p] = NN;  // sentinel -> zero row
        if (lane == 0) cnt[row] = nn;
    } else if (b < 2336) {
        int bb = b - 2048;
        const float* Wa;
        const float* Wb;
        int tile, gbase;
        if (bb < 64)       { Wa = W1r; Wb = W1s; tile = bb;       gbase = 0; }
        else if (bb < 128) { Wa = W2r; Wb = W2s; tile = bb - 64;  gbase = 64; }
        else if (bb < 192) { Wa = W3r; Wb = W3s; tile = bb - 128; gbase = 128; }
        else               { Wa = Wl;  Wb = nullptr; tile = bb - 192; gbase = 192; }
        int kt = tile >> 3, nt = tile & 7;
        int lane = tid & 63, i0 = (tid >> 6) * 2;
        int n = nt * 16 + (lane & 15);
        u16* dst = wfrag + ((size_t)(gbase + tile) * 64 + lane) * 8;
#pragma unroll
        for (int ii = 0; ii < 2; ++ii) {
            int i = i0 + ii;
            int k = kt * 32 + ((lane >> 4) * 8) + i;
            float v;
            if (Wb) v = (k < 128) ? Wa[k * CC + n] : Wb[(k - 128) * CC + n];
            else    v = Wa[k * CC + n];
            dst[i] = f2bf(v);
        }
    } else if (b < 3360) {
        int idx = (b - 2336) * 1024 + tid * 4;
        float4 v = *(const float4*)(x0 + idx);
        ushort4 o;
        o.x = f2bf(v.x); o.y = f2bf(v.y); o.z = f2bf(v.z); o.w = f2bf(v.w);
        *(ushort4*)(x0bf + idx) = o;
    } else {
        if (tid < 128) {
            x0bf[(size_t)NN * CC + tid] = 0;
            yp1[(size_t)NN * CC + tid] = 0;
            yp2[(size_t)NN * CC + tid] = 0;
            yp3[(size_t)NN * CC + tid] = 0;
            coefs[tid] = 1.f;        // layer-0 identity affine
            coefs[128 + tid] = 0.f;
        }
        if (tid < 3) counters[tid] = 0;
    }
}

// ============ k_agg: Ab[row] = [a*sum_nbr(src)+b*n | a*src[row]+b] (bf16) ============
__global__ __launch_bounds__(256) void k_agg(const u16* __restrict__ src,
                                             const float* __restrict__ coef,
                                             const int* __restrict__ nbr,
                                             const int* __restrict__ cnt,
                                             u16* __restrict__ Ab) {
    int row = blockIdx.x * 4 + (threadIdx.x >> 6);
    int lane = threadIdx.x & 63;
    int c = lane * 2;
    int nreal = cnt[row];
    int npad = (nreal + 3) & ~3;
    const int* nb = nbr + (size_t)row * CAP;
    float a0 = 0.f, a1 = 0.f;
    for (int j = 0; j < npad; j += 4) {
        int4 m = *(const int4*)(nb + j);
        uint32 v0 = *(const uint32*)(src + (size_t)m.x * CC + c);
        uint32 v1 = *(const uint32*)(src + (size_t)m.y * CC + c);
        uint32 v2 = *(const uint32*)(src + (size_t)m.z * CC + c);
        uint32 v3 = *(const uint32*)(src + (size_t)m.w * CC + c);
        a0 += bf2f(v0 & 0xffffu); a1 += bf2f(v0 >> 16);
        a0 += bf2f(v1 & 0xffffu); a1 += bf2f(v1 >> 16);
        a0 += bf2f(v2 & 0xffffu); a1 += bf2f(v2 >> 16);
        a0 += bf2f(v3 & 0xffffu); a1 += bf2f(v3 >> 16);
    }
    float ca0 = coef[c], ca1 = coef[c + 1];
    float cb0 = coef[128 + c], cb1 = coef[128 + c + 1];
    float fn = (float)nreal;
    uint32 rv = *(const uint32*)(src + (size_t)row * CC + c);
    u16* dst = Ab + (size_t)row * 256;
    *(uint32*)(dst + c) = pack2(ca0 * a0 + cb0 * fn, ca1 * a1 + cb1 * fn);
    *(uint32*)(dst + 128 + c) = pack2(ca0 * bf2f(rv & 0xffffu) + cb0,
                                      ca1 * bf2f(rv >> 16) + cb1);
}

// ============ k_gemm: yp = relu(Ab @ [Wr;Ws] + b) -> bf16, BN stats via last block ============
__global__ __launch_bounds__(256) void k_gemm(const u16* __restrict__ Ab,
                                              const u16* __restrict__ wfrag,
                                              const float* __restrict__ bias,
                                              u16* __restrict__ yp,
                                              float* __restrict__ partials,
                                              const float* __restrict__ g,
                                              const float* __restrict__ be,
                                              float* __restrict__ coefOut,
                                              uint32* __restrict__ counter) {
    __shared__ u16 A[32][264];  // +8 pad
    __shared__ float sSum[CC], sSq[CC];
    __shared__ bool isLast;
    int tid = threadIdx.x, lane = tid & 63, wid = tid >> 6;
    int row0 = blockIdx.x * 32;
    if (tid < CC) { sSum[tid] = 0.f; sSq[tid] = 0.f; }
    for (int i = tid; i < 1024; i += 256) {
        int r = i >> 5, k = (i & 31) * 8;
        *(uint4*)&A[r][k] = *(const uint4*)(Ab + (size_t)(row0 + r) * 256 + k);
    }
    __syncthreads();

    int mh = wid >> 1, nh = wid & 1;
    int arow = mh * 16 + (lane & 15);
    int kg = (lane >> 4) * 8;
    f32x4 acc[4];
#pragma unroll
    for (int nt = 0; nt < 4; ++nt) acc[nt] = (f32x4){0.f, 0.f, 0.f, 0.f};
#pragma unroll
    for (int kt = 0; kt < 8; ++kt) {
        bf16x8 a = *(const bf16x8*)&A[arow][kt * 32 + kg];
        const u16* wb = wfrag + ((size_t)(kt * 8 + nh * 4) * 64 + lane) * 8;
#pragma unroll
        for (int nt = 0; nt < 4; ++nt) {
            bf16x8 bfr = *(const bf16x8*)(wb + (size_t)nt * 512);
            acc[nt] = __builtin_amdgcn_mfma_f32_16x16x32_bf16(a, bfr, acc[nt], 0, 0, 0);
        }
    }
    int rowb = row0 + mh * 16 + ((lane >> 4) * 4);
#pragma unroll
    for (int nt = 0; nt < 4; ++nt) {
        int col = nh * 64 + nt * 16 + (lane & 15);
        float bv = bias[col];
        float s1 = 0.f, s2 = 0.f;
#pragma unroll
        for (int q = 0; q < 4; ++q) {
            float y = acc[nt][q] + bv;
            y = y > 0.f ? y : 0.f;
            yp[(size_t)(rowb + q) * CC + col] = f2bf(y);
            s1 += y;
            s2 += y * y;
        }
        s1 += __shfl_xor(s1, 16); s1 += __shfl_xor(s1, 32);
        s2 += __shfl_xor(s2, 16); s2 += __shfl_xor(s2, 32);
        if ((lane >> 4) == 0) { atomicAdd(&sSum[col], s1); atomicAdd(&sSq[col], s2); }
    }
    __syncthreads();
    if (tid < CC) {
        partials[(size_t)blockIdx.x * 256 + tid] = sSum[tid];
        partials[(size_t)blockIdx.x * 256 + CC + tid] = sSq[tid];
    }
    // ---- last block finalizes BN affine coef ----
    __threadfence();
    if (tid == 0) isLast = (atomicAdd(counter, 1u) == 255u);
    __syncthreads();
    if (isLast) {
        float acc2 = 0.f;
#pragma unroll 4
        for (int b = 0; b < 256; ++b) acc2 += partials[b * 256 + tid];
        sSum[tid & 127] = 0.f;  // reuse LDS: [0..127]=sum, use sSq for sq
        __syncthreads();
        if (tid < 128) sSum[tid] = acc2;
        else sSq[tid - 128] = acc2;
        __syncthreads();
        if (tid < 128) {
            float mu = sSum[tid] * (1.f / NN);
            float var = sSq[tid] * (1.f / NN) - mu * mu;
            float rs = rsqrtf(var + 1e-5f);
            float a = g[tid] * rs;
            coefOut[tid] = a;
            coefOut[128 + tid] = be[tid] - mu * a;
        }
    }
}

// ============ k_final: s-GEMM + team embeddings + xcat normalize, by block range ============
// blocks [0,256): s tile; [256,768): team t=b-256; [768,3840): xcat normalize
__global__ __launch_bounds__(256) void k_final(
    const u16* __restrict__ yp1, const u16* __restrict__ yp2, const u16* __restrict__ yp3,
    const float* __restrict__ coefs,  // [3][256]
    const u16* __restrict__ wfrag, const float* __restrict__ bias,
    const int* __restrict__ teams, const int* __restrict__ slen_p,
    const float* __restrict__ att,
    float* __restrict__ sout, float* __restrict__ xcat,
    float* __restrict__ oT, float* __restrict__ oS, float* __restrict__ oR) {
    int b = blockIdx.x, tid = threadIdx.x;
    if (b < 256) {
        __shared__ u16 A[32][392];  // 384 + 8 pad
        int lane = tid & 63, wid = tid >> 6;
        int row0 = b * 32;
        for (int i = tid; i < 1536; i += 256) {
            int r = i / 48, kk = (i % 48) * 8;
            int seg = kk >> 7, c = kk & 127;
            const u16* sp = (seg == 0 ? yp1 : seg == 1 ? yp2 : yp3) + (size_t)(row0 + r) * CC + c;
            uint4 raw = *(const uint4*)sp;
            const float* cf = coefs + seg * 256;
            float4 av0 = *(const float4*)(cf + c);
            float4 av1 = *(const float4*)(cf + c + 4);
            float4 bv0 = *(const float4*)(cf + 128 + c);
            float4 bv1 = *(const float4*)(cf + 128 + c + 4);
            uint4 o;
            o.x = pack2(av0.x * bf2f(raw.x & 0xffffu) + bv0.x, av0.y * bf2f(raw.x >> 16) + bv0.y);
            o.y = pack2(av0.z * bf2f(raw.y & 0xffffu) + bv0.z, av0.w * bf2f(raw.y >> 16) + bv0.w);
            o.z = pack2(av1.x * bf2f(raw.z & 0xffffu) + bv1.x, av1.y * bf2f(raw.z >> 16) + bv1.y);
            o.w = pack2(av1.z * bf2f(raw.w & 0xffffu) + bv1.z, av1.w * bf2f(raw.w >> 16) + bv1.w);
            *(uint4*)&A[r][kk] = o;
        }
        __syncthreads();
        int mh = wid >> 1, nh = wid & 1;
        int arow = mh * 16 + (lane & 15);
        int kg = (lane >> 4) * 8;
        f32x4 acc[4];
#pragma unroll
        for (int nt = 0; nt < 4; ++nt) acc[nt] = (f32x4){0.f, 0.f, 0.f, 0.f};
#pragma unroll
        for (int kt = 0; kt < 12; ++kt) {
            bf16x8 a = *(const bf16x8*)&A[arow][kt * 32 + kg];
            const u16* wb = wfrag + ((size_t)(kt * 8 + nh * 4) * 64 + lane) * 8;
#pragma unroll
            for (int nt = 0; nt < 4; ++nt) {
                bf16x8 bfr = *(const bf16x8*)(wb + (size_t)nt * 512);
                acc[nt] = __builtin_amdgcn_mfma_f32_16x16x32_bf16(a, bfr, acc[nt], 0, 0, 0);
            }
        }
        int rowb = row0 + mh * 16 + ((lane >> 4) * 4);
#pragma unroll
        for (int nt = 0; nt < 4; ++nt) {
            int col = nh * 64 + nt * 16 + (lane & 15);
            float bv = bias[col];
#pragma unroll
            for (int q = 0; q < 4; ++q) {
                float y = acc[nt][q] + bv;
                sout[(size_t)(rowb + q) * CC + col] = y > 0.f ? y : 0.f;
            }
        }
    } else if (b < 768) {
        __shared__ float wT[LL], wS[LL], wR[LL];
        __shared__ int ids[LL];
        int t = b - 256;
        if (tid < 64) {
            int lane = tid;
            bool act = lane < LL;
            float a = act ? att[t * LL + lane] : 0.f;
            int id = act ? teams[t * LL + lane] : NN;
            if (act) ids[lane] = id;
            int sl = *slen_p;
            const float NEG = -1e30f;
            float mT = NEG, eT, sT;
            float v;
            v = act ? a : NEG;
#pragma unroll
            for (int o = 32; o > 0; o >>= 1) v = fmaxf(v, __shfl_xor(v, o));
            mT = v;
            eT = act ? __expf(a - mT) : 0.f;
            v = eT;
#pragma unroll
            for (int o = 32; o > 0; o >>= 1) v += __shfl_xor(v, o);
            sT = v;
            bool inS = act && (lane < sl);
            v = inS ? a : NEG;
#pragma unroll
            for (int o = 32; o > 0; o >>= 1) v = fmaxf(v, __shfl_xor(v, o));
            float mS = v;
            float eS = inS ? __expf(a - mS) : 0.f;
            v = eS;
#pragma unroll
            for (int o = 32; o > 0; o >>= 1) v += __shfl_xor(v, o);
            float sS = v;
            bool inR = act && (lane >= sl) && (id != NN);
            v = inR ? a : NEG;
#pragma unroll
            for (int o = 32; o > 0; o >>= 1) v = fmaxf(v, __shfl_xor(v, o));
            float mR = v;
            float eR = inR ? __expf(a - mR) : 0.f;
            v = eR;
#pragma unroll
            for (int o = 32; o > 0; o >>= 1) v += __shfl_xor(v, o);
            float sR = v;
            if (act) {
                wT[lane] = eT / sT;
                wS[lane] = eS / sS;
                wR[lane] = eR / sR;
            }
        }
        __syncthreads();
        for (int d = tid; d < 384; d += 256) {
            int seg = d >> 7, c = d & 127;
            const u16* xb = seg == 0 ? yp1 : seg == 1 ? yp2 : yp3;
            float ca = coefs[seg * 256 + c];
            float cb = coefs[seg * 256 + 128 + c];
            float aT = 0.f, aS = 0.f, aR = 0.f;
            for (int l = 0; l < LL; ++l) {
                int id = ids[l];
                if (id < NN) {
                    float vv = ca * bf2f((uint32)xb[(size_t)id * CC + c]) + cb;
                    aT += wT[l] * vv;
                    aS += wS[l] * vv;
                    aR += wR[l] * vv;
                }
            }
            oT[(size_t)t * 384 + d] = aT;
            oS[(size_t)t * 384 + d] = aS;
            oR[(size_t)t * 384 + d] = aR;
        }
    } else {
        int idx = (b - 768) * 256 + tid;  // one per 4 f32
        int n = idx / 96;
        int k = (idx % 96) * 4;
        int seg = k >> 7, c = k & 127;
        const u16* sp = (seg == 0 ? yp1 : seg == 1 ? yp2 : yp3) + (size_t)n * CC + c;
        ushort4 raw = *(const ushort4*)sp;
        const float* cf = coefs + seg * 256;
        float4 a = *(const float4*)(cf + c);
        float4 bb = *(const float4*)(cf + 128 + c);
        float4 o;
        o.x = a.x * bf2f((uint32)raw.x) + bb.x;
        o.y = a.y * bf2f((uint32)raw.y) + bb.y;
        o.z = a.z * bf2f((uint32)raw.z) + bb.z;
        o.w = a.w * bf2f((uint32)raw.w) + bb.w;
        *(float4*)(xcat + (size_t)n * 384 + k) = o;
    }
}

extern "C" void kernel_launch(void* const* d_in, const int* in_sizes, int n_in,
                              void* d_out, int out_size, void* d_ws, size_t ws_size,
                              hipStream_t stream) {
    const float* x = (const float*)d_in[0];
    const float* adj = (const float*)d_in[1];
    const int* teams = (const int*)d_in[2];
    const int* slen = (const int*)d_in[3];
    const float* W1r = (const float*)d_in[4];
    const float* b1 = (const float*)d_in[5];
    const float* W1s = (const float*)d_in[6];
    const float* W2r = (const float*)d_in[7];
    const float* b2 = (const float*)d_in[8];
    const float* W2s = (const float*)d_in[9];
    const float* W3r = (const float*)d_in[10];
    const float* b3 = (const float*)d_in[11];
    const float* W3s = (const float*)d_in[12];
    const float* g1 = (const float*)d_in[13];
    const float* be1 = (const float*)d_in[14];
    const float* g2 = (const float*)d_in[15];
    const float* be2 = (const float*)d_in[16];
    const float* g3 = (const float*)d_in[17];
    const float* be3 = (const float*)d_in[18];
    const float* Wl = (const float*)d_in[19];
    const float* bl = (const float*)d_in[20];
    const float* att = (const float*)d_in[21];

    float* out = (float*)d_out;
    float* s_out = out;
    float* xcat = out + (size_t)NN * CC;
    float* oT = xcat + (size_t)NN * 384;
    float* oS = oT + (size_t)TT * 384;
    float* oR = oS + (size_t)TT * 384;

    char* ws = (char*)d_ws;
    size_t off = 0;
    int* nbr = (int*)(ws + off); off += (size_t)NN * CAP * 4;
    int* cnt = (int*)(ws + off); off += (size_t)NN * 4;
    u16* x0bf = (u16*)(ws + off); off += (size_t)(NN + 1) * CC * 2;
    u16* yp1 = (u16*)(ws + off); off += (size_t)(NN + 1) * CC * 2;
    u16* yp2 = (u16*)(ws + off); off += (size_t)(NN + 1) * CC * 2;
    u16* yp3 = (u16*)(ws + off); off += (size_t)(NN + 1) * CC * 2;
    u16* Ab = (u16*)(ws + off); off += (size_t)NN * 256 * 2;
    u16* wfrag = (u16*)(ws + off); off += (size_t)288 * 512 * 2;
    float* partials = (float*)(ws + off); off += (size_t)256 * 256 * 4;
    float* coefs = (float*)(ws + off); off += (size_t)4 * 256 * 4;  // [identity, c1, c2, c3]
    uint32* counters = (uint32*)(ws + off); off += 16;

    k_init<<<3361, 256, 0, stream>>>(adj, W1r, W1s, W2r, W2s, W3r, W3s, Wl, x,
                                     nbr, cnt, wfrag, x0bf, yp1, yp2, yp3, coefs, counters);
    // layer 1
    k_agg<<<2048, 256, 0, stream>>>(x0bf, coefs, nbr, cnt, Ab);
    k_gemm<<<256, 256, 0, stream>>>(Ab, wfrag, b1, yp1, partials,
                                    g1, be1, coefs + 256, counters + 0);
    // layer 2
    k_agg<<<2048, 256, 0, stream>>>(yp1, coefs + 256, nbr, cnt, Ab);
    k_gemm<<<256, 256, 0, stream>>>(Ab, wfrag + 64 * 512, b2, yp2, partials,
                                    g2, be2, coefs + 512, counters + 1);
    // layer 3
    k_agg<<<2048, 256, 0, stream>>>(yp2, coefs + 512, nbr, cnt, Ab);
    k_gemm<<<256, 256, 0, stream>>>(Ab, wfrag + 128 * 512, b3, yp3, partials,
                                    g3, be3, coefs + 768, counters + 2);
    // final: s + team embeddings + xcat
    k_final<<<3840, 256, 0, stream>>>(yp1, yp2, yp3, coefs + 256,
                                      wfrag + 192 * 512, bl, teams, slen, att,
                                      s_out, xcat, oT, oS, oR);
}

// Round 4
// 137.554 us; speedup vs baseline: 1.6519x; 1.6519x over previous
//
#include <hip/hip_runtime.h>
#include <stdint.h>

#define NN 8192
#define CC 128
#define TT 512
#define LL 30
#define CAP 64

typedef unsigned int uint32;
typedef unsigned short u16;

typedef float f32x4 __attribute__((ext_vector_type(4)));
typedef short bf16x8 __attribute__((ext_vector_type(8)));

__device__ __forceinline__ float bf2f(uint32 h) { return __uint_as_float(h << 16); }
__device__ __forceinline__ u16 f2bf(float f) {
    uint32 u = __float_as_uint(f);
    u = (u + 0x7fffu + ((u >> 16) & 1u)) >> 16;
    return (u16)u;
}
__device__ __forceinline__ uint32 pack2(float a, float b) {
    return (uint32)f2bf(a) | ((uint32)f2bf(b) << 16);
}

// ---- shared BN-stats finalize: partials[256][256] -> affine coef (1 block, 256 thr) ----
__device__ __forceinline__ void stats_reduce(const float* __restrict__ P,
                                             const float* __restrict__ g,
                                             const float* __restrict__ be,
                                             float* __restrict__ coefOut, int tid) {
    __shared__ float SS[256], QQ[256];
    int c = tid & 127, half = tid >> 7;
    float s = 0.f, q = 0.f;
    int b0 = half * 128;
#pragma unroll 8
    for (int b = b0; b < b0 + 128; ++b) {
        s += P[b * 256 + c];
        q += P[b * 256 + 128 + c];
    }
    SS[tid] = s; QQ[tid] = q;
    __syncthreads();
    if (tid < 128) {
        float sum = SS[tid] + SS[tid + 128];
        float sq = QQ[tid] + QQ[tid + 128];
        float mu = sum * (1.f / NN);
        float var = sq * (1.f / NN) - mu * mu;
        float rs = rsqrtf(var + 1e-5f);
        float a = g[tid] * rs;
        coefOut[tid] = a;
        coefOut[128 + tid] = be[tid] - mu * a;
    }
}

// ============ k_pre: adj scan + W frag pack + x0->bf16 + zero rows/identity coef ============
// blocks [0,2048): adj rows; [2048,2336): wfrag; [2336,3360): x0 convert; 3360: small init
__global__ __launch_bounds__(256) void k_pre(
    const float* __restrict__ adj,
    const float* __restrict__ W1r, const float* __restrict__ W1s,
    const float* __restrict__ W2r, const float* __restrict__ W2s,
    const float* __restrict__ W3r, const float* __restrict__ W3s,
    const float* __restrict__ Wl, const float* __restrict__ x0,
    int* __restrict__ nbr, int* __restrict__ cnt,
    u16* __restrict__ wfrag, u16* __restrict__ x0bf,
    u16* __restrict__ yp1, u16* __restrict__ yp2, u16* __restrict__ yp3,
    float* __restrict__ coefs) {
    int b = blockIdx.x, tid = threadIdx.x;
    if (b < 2048) {
        int row = b * 4 + (tid >> 6);
        int lane = tid & 63;
        const float4* arow = (const float4*)(adj + (size_t)row * NN);
        int base = 0;
        int* dst = nbr + (size_t)row * CAP;
        for (int it = 0; it < 32; ++it) {
            float4 v = arow[it * 64 + lane];
            float vv[4] = {v.x, v.y, v.z, v.w};
#pragma unroll
            for (int j = 0; j < 4; ++j) {
                unsigned long long m = __ballot(vv[j] != 0.f);
                if (vv[j] != 0.f) {
                    int pos = base + __popcll(m & ((1ull << lane) - 1ull));
                    if (pos < CAP) dst[pos] = it * 256 + lane * 4 + j;
                }
                base += __popcll(m);
            }
        }
        int nn = base < CAP ? base : CAP;
        int npad = (nn + 3) & ~3;
        for (int p = nn + lane; p < npad; p += 64) dst[p] = NN;  // sentinel -> zero row
        if (lane == 0) cnt[row] = nn;
    } else if (b < 2336) {
        int bb = b - 2048;
        const float* Wa;
        const float* Wb;
        int tile, gbase;
        if (bb < 64)       { Wa = W1r; Wb = W1s; tile = bb;       gbase = 0; }
        else if (bb < 128) { Wa = W2r; Wb = W2s; tile = bb - 64;  gbase = 64; }
        else if (bb < 192) { Wa = W3r; Wb = W3s; tile = bb - 128; gbase = 128; }
        else               { Wa = Wl;  Wb = nullptr; tile = bb - 192; gbase = 192; }
        int kt = tile >> 3, nt = tile & 7;
        int lane = tid & 63, i0 = (tid >> 6) * 2;
        int n = nt * 16 + (lane & 15);
        u16* dst = wfrag + ((size_t)(gbase + tile) * 64 + lane) * 8;
#pragma unroll
        for (int ii = 0; ii < 2; ++ii) {
            int i = i0 + ii;
            int k = kt * 32 + ((lane >> 4) * 8) + i;
            float v;
            if (Wb) v = (k < 128) ? Wa[k * CC + n] : Wb[(k - 128) * CC + n];
            else    v = Wa[k * CC + n];
            dst[i] = f2bf(v);
        }
    } else if (b < 3360) {
        int idx = (b - 2336) * 1024 + tid * 4;
        float4 v = *(const float4*)(x0 + idx);
        ushort4 o;
        o.x = f2bf(v.x); o.y = f2bf(v.y); o.z = f2bf(v.z); o.w = f2bf(v.w);
        *(ushort4*)(x0bf + idx) = o;
    } else {
        if (tid < 128) {
            x0bf[(size_t)NN * CC + tid] = 0;
            yp1[(size_t)NN * CC + tid] = 0;
            yp2[(size_t)NN * CC + tid] = 0;
            yp3[(size_t)NN * CC + tid] = 0;
            coefs[tid] = 1.f;        // layer-0 identity affine
            coefs[128 + tid] = 0.f;
        }
    }
}

// ============ k_agg: Abraw[row] = sum_nbr(src) (raw, bf16); block 2048 = prev-layer BN stats ============
__global__ __launch_bounds__(256) void k_agg(const u16* __restrict__ src,
                                             const int* __restrict__ nbr,
                                             const int* __restrict__ cnt,
                                             u16* __restrict__ Abraw,
                                             const float* __restrict__ P,
                                             const float* __restrict__ g,
                                             const float* __restrict__ be,
                                             float* __restrict__ coefOut) {
    if (blockIdx.x >= 2048) {  // hidden stats block (only launched for layers 2,3)
        stats_reduce(P, g, be, coefOut, threadIdx.x);
        return;
    }
    int row = blockIdx.x * 4 + (threadIdx.x >> 6);
    int lane = threadIdx.x & 63;
    int c = lane * 2;
    int nreal = cnt[row];
    int npad = (nreal + 3) & ~3;
    const int* nb = nbr + (size_t)row * CAP;
    float a0 = 0.f, a1 = 0.f;
    for (int j = 0; j < npad; j += 4) {
        int4 m = *(const int4*)(nb + j);
        uint32 v0 = *(const uint32*)(src + (size_t)m.x * CC + c);
        uint32 v1 = *(const uint32*)(src + (size_t)m.y * CC + c);
        uint32 v2 = *(const uint32*)(src + (size_t)m.z * CC + c);
        uint32 v3 = *(const uint32*)(src + (size_t)m.w * CC + c);
        a0 += bf2f(v0 & 0xffffu); a1 += bf2f(v0 >> 16);
        a0 += bf2f(v1 & 0xffffu); a1 += bf2f(v1 >> 16);
        a0 += bf2f(v2 & 0xffffu); a1 += bf2f(v2 >> 16);
        a0 += bf2f(v3 & 0xffffu); a1 += bf2f(v3 >> 16);
    }
    *(uint32*)(Abraw + (size_t)row * CC + c) = pack2(a0, a1);
}

// ============ k_gemm: stage A=[a*agg+b*n | a*y+b], yp = relu(A@[Wr;Ws]+bias), BN partials ============
__global__ __launch_bounds__(256) void k_gemm(const u16* __restrict__ Abraw,
                                              const u16* __restrict__ yprev,
                                              const int* __restrict__ cnt,
                                              const u16* __restrict__ wfrag,
                                              const float* __restrict__ bias,
                                              const float* __restrict__ coefIn,
                                              u16* __restrict__ yp,
                                              float* __restrict__ partials) {
    __shared__ u16 A[32][264];  // +8 pad
    __shared__ float sSum[CC], sSq[CC];
    int tid = threadIdx.x, lane = tid & 63, wid = tid >> 6;
    int row0 = blockIdx.x * 32;
    if (tid < CC) { sSum[tid] = 0.f; sSq[tid] = 0.f; }
    for (int i = tid; i < 1024; i += 256) {
        int r = i >> 5, k = (i & 31) * 8;
        int row = row0 + r;
        uint4 raw;
        float fn;
        int c;
        if (k < 128) {
            c = k;
            raw = *(const uint4*)(Abraw + (size_t)row * CC + k);
            fn = (float)cnt[row];
        } else {
            c = k - 128;
            raw = *(const uint4*)(yprev + (size_t)row * CC + c);
            fn = 1.f;
        }
        float4 a0 = *(const float4*)(coefIn + c);
        float4 a1 = *(const float4*)(coefIn + c + 4);
        float4 b0 = *(const float4*)(coefIn + 128 + c);
        float4 b1 = *(const float4*)(coefIn + 128 + c + 4);
        uint4 o;
        o.x = pack2(a0.x * bf2f(raw.x & 0xffffu) + b0.x * fn, a0.y * bf2f(raw.x >> 16) + b0.y * fn);
        o.y = pack2(a0.z * bf2f(raw.y & 0xffffu) + b0.z * fn, a0.w * bf2f(raw.y >> 16) + b0.w * fn);
        o.z = pack2(a1.x * bf2f(raw.z & 0xffffu) + b1.x * fn, a1.y * bf2f(raw.z >> 16) + b1.y * fn);
        o.w = pack2(a1.z * bf2f(raw.w & 0xffffu) + b1.z * fn, a1.w * bf2f(raw.w >> 16) + b1.w * fn);
        *(uint4*)&A[r][k] = o;
    }
    __syncthreads();

    int mh = wid >> 1, nh = wid & 1;
    int arow = mh * 16 + (lane & 15);
    int kg = (lane >> 4) * 8;
    f32x4 acc[4];
#pragma unroll
    for (int nt = 0; nt < 4; ++nt) acc[nt] = (f32x4){0.f, 0.f, 0.f, 0.f};
#pragma unroll
    for (int kt = 0; kt < 8; ++kt) {
        bf16x8 a = *(const bf16x8*)&A[arow][kt * 32 + kg];
        const u16* wb = wfrag + ((size_t)(kt * 8 + nh * 4) * 64 + lane) * 8;
#pragma unroll
        for (int nt = 0; nt < 4; ++nt) {
            bf16x8 bfr = *(const bf16x8*)(wb + (size_t)nt * 512);
            acc[nt] = __builtin_amdgcn_mfma_f32_16x16x32_bf16(a, bfr, acc[nt], 0, 0, 0);
        }
    }
    int rowb = row0 + mh * 16 + ((lane >> 4) * 4);
#pragma unroll
    for (int nt = 0; nt < 4; ++nt) {
        int col = nh * 64 + nt * 16 + (lane & 15);
        float bv = bias[col];
        float s1 = 0.f, s2 = 0.f;
#pragma unroll
        for (int q = 0; q < 4; ++q) {
            float y = acc[nt][q] + bv;
            y = y > 0.f ? y : 0.f;
            yp[(size_t)(rowb + q) * CC + col] = f2bf(y);
            s1 += y;
            s2 += y * y;
        }
        s1 += __shfl_xor(s1, 16); s1 += __shfl_xor(s1, 32);
        s2 += __shfl_xor(s2, 16); s2 += __shfl_xor(s2, 32);
        if ((lane >> 4) == 0) { atomicAdd(&sSum[col], s1); atomicAdd(&sSq[col], s2); }
    }
    __syncthreads();
    if (tid < CC) {
        partials[(size_t)blockIdx.x * 256 + tid] = sSum[tid];
        partials[(size_t)blockIdx.x * 256 + CC + tid] = sSq[tid];
    }
}

// ============ k_coef3: finalize layer-3 BN coef (1 block) ============
__global__ __launch_bounds__(256) void k_coef3(const float* __restrict__ P,
                                               const float* __restrict__ g,
                                               const float* __restrict__ be,
                                               float* __restrict__ coefOut) {
    stats_reduce(P, g, be, coefOut, threadIdx.x);
}

// ============ k_gfinal: s = relu([y1n|y2n|y3n] @ Wl + bl) ============
__global__ __launch_bounds__(256) void k_gfinal(const u16* __restrict__ yp1,
                                                const u16* __restrict__ yp2,
                                                const u16* __restrict__ yp3,
                                                const float* __restrict__ coefs,  // [3][256]
                                                const u16* __restrict__ wfrag,
                                                const float* __restrict__ bias,
                                                float* __restrict__ sout) {
    __shared__ u16 A[32][392];  // 384 + 8 pad
    int tid = threadIdx.x, lane = tid & 63, wid = tid >> 6;
    int row0 = blockIdx.x * 32;
    for (int i = tid; i < 1536; i += 256) {
        int r = i / 48, kk = (i % 48) * 8;
        int seg = kk >> 7, c = kk & 127;
        const u16* sp = (seg == 0 ? yp1 : seg == 1 ? yp2 : yp3) + (size_t)(row0 + r) * CC + c;
        uint4 raw = *(const uint4*)sp;
        const float* cf = coefs + seg * 256;
        float4 av0 = *(const float4*)(cf + c);
        float4 av1 = *(const float4*)(cf + c + 4);
        float4 bv0 = *(const float4*)(cf + 128 + c);
        float4 bv1 = *(const float4*)(cf + 128 + c + 4);
        uint4 o;
        o.x = pack2(av0.x * bf2f(raw.x & 0xffffu) + bv0.x, av0.y * bf2f(raw.x >> 16) + bv0.y);
        o.y = pack2(av0.z * bf2f(raw.y & 0xffffu) + bv0.z, av0.w * bf2f(raw.y >> 16) + bv0.w);
        o.z = pack2(av1.x * bf2f(raw.z & 0xffffu) + bv1.x, av1.y * bf2f(raw.z >> 16) + bv1.y);
        o.w = pack2(av1.z * bf2f(raw.w & 0xffffu) + bv1.z, av1.w * bf2f(raw.w >> 16) + bv1.w);
        *(uint4*)&A[r][kk] = o;
    }
    __syncthreads();
    int mh = wid >> 1, nh = wid & 1;
    int arow = mh * 16 + (lane & 15);
    int kg = (lane >> 4) * 8;
    f32x4 acc[4];
#pragma unroll
    for (int nt = 0; nt < 4; ++nt) acc[nt] = (f32x4){0.f, 0.f, 0.f, 0.f};
#pragma unroll
    for (int kt = 0; kt < 12; ++kt) {
        bf16x8 a = *(const bf16x8*)&A[arow][kt * 32 + kg];
        const u16* wb = wfrag + ((size_t)(kt * 8 + nh * 4) * 64 + lane) * 8;
#pragma unroll
        for (int nt = 0; nt < 4; ++nt) {
            bf16x8 bfr = *(const bf16x8*)(wb + (size_t)nt * 512);
            acc[nt] = __builtin_amdgcn_mfma_f32_16x16x32_bf16(a, bfr, acc[nt], 0, 0, 0);
        }
    }
    int rowb = row0 + mh * 16 + ((lane >> 4) * 4);
#pragma unroll
    for (int nt = 0; nt < 4; ++nt) {
        int col = nh * 64 + nt * 16 + (lane & 15);
        float bv = bias[col];
#pragma unroll
        for (int q = 0; q < 4; ++q) {
            float y = acc[nt][q] + bv;
            sout[(size_t)(rowb + q) * CC + col] = y > 0.f ? y : 0.f;
        }
    }
}

// ============ k_tail: team embeddings [0,512) + xcat normalize [512,3584) ============
__global__ __launch_bounds__(256) void k_tail(
    const u16* __restrict__ yp1, const u16* __restrict__ yp2, const u16* __restrict__ yp3,
    const float* __restrict__ coefs,  // [3][256]
    const int* __restrict__ teams, const int* __restrict__ slen_p,
    const float* __restrict__ att,
    float* __restrict__ xcat,
    float* __restrict__ oT, float* __restrict__ oS, float* __restrict__ oR) {
    int b = blockIdx.x, tid = threadIdx.x;
    if (b < 512) {
        __shared__ float wT[LL], wS[LL], wR[LL];
        __shared__ int ids[LL];
        int t = b;
        if (tid < 64) {
            int lane = tid;
            bool act = lane < LL;
            float a = act ? att[t * LL + lane] : 0.f;
            int id = act ? teams[t * LL + lane] : NN;
            if (act) ids[lane] = id;
            int sl = *slen_p;
            const float NEG = -1e30f;
            float v = act ? a : NEG;
#pragma unroll
            for (int o = 32; o > 0; o >>= 1) v = fmaxf(v, __shfl_xor(v, o));
            float mT = v;
            float eT = act ? __expf(a - mT) : 0.f;
            v = eT;
#pragma unroll
            for (int o = 32; o > 0; o >>= 1) v += __shfl_xor(v, o);
            float sT = v;
            bool inS = act && (lane < sl);
            v = inS ? a : NEG;
#pragma unroll
            for (int o = 32; o > 0; o >>= 1) v = fmaxf(v, __shfl_xor(v, o));
            float mS = v;
            float eS = inS ? __expf(a - mS) : 0.f;
            v = eS;
#pragma unroll
            for (int o = 32; o > 0; o >>= 1) v += __shfl_xor(v, o);
            float sS = v;
            bool inR = act && (lane >= sl) && (id != NN);
            v = inR ? a : NEG;
#pragma unroll
            for (int o = 32; o > 0; o >>= 1) v = fmaxf(v, __shfl_xor(v, o));
            float mR = v;
            float eR = inR ? __expf(a - mR) : 0.f;
            v = eR;
#pragma unroll
            for (int o = 32; o > 0; o >>= 1) v += __shfl_xor(v, o);
            float sR = v;
            if (act) {
                wT[lane] = eT / sT;
                wS[lane] = eS / sS;
                wR[lane] = eR / sR;
            }
        }
        __syncthreads();
        for (int d = tid; d < 384; d += 256) {
            int seg = d >> 7, c = d & 127;
            const u16* xb = seg == 0 ? yp1 : seg == 1 ? yp2 : yp3;
            float ca = coefs[seg * 256 + c];
            float cb = coefs[seg * 256 + 128 + c];
            float aT = 0.f, aS = 0.f, aR = 0.f;
            for (int l = 0; l < LL; ++l) {
                int id = ids[l];
                if (id < NN) {
                    float vv = ca * bf2f((uint32)xb[(size_t)id * CC + c]) + cb;
                    aT += wT[l] * vv;
                    aS += wS[l] * vv;
                    aR += wR[l] * vv;
                }
            }
            oT[(size_t)t * 384 + d] = aT;
            oS[(size_t)t * 384 + d] = aS;
            oR[(size_t)t * 384 + d] = aR;
        }
    } else {
        int idx = (b - 512) * 256 + tid;  // one per 4 f32
        int n = idx / 96;
        int k = (idx % 96) * 4;
        int seg = k >> 7, c = k & 127;
        const u16* sp = (seg == 0 ? yp1 : seg == 1 ? yp2 : yp3) + (size_t)n * CC + c;
        ushort4 raw = *(const ushort4*)sp;
        const float* cf = coefs + seg * 256;
        float4 a = *(const float4*)(cf + c);
        float4 bb = *(const float4*)(cf + 128 + c);
        float4 o;
        o.x = a.x * bf2f((uint32)raw.x) + bb.x;
        o.y = a.y * bf2f((uint32)raw.y) + bb.y;
        o.z = a.z * bf2f((uint32)raw.z) + bb.z;
        o.w = a.w * bf2f((uint32)raw.w) + bb.w;
        *(float4*)(xcat + (size_t)n * 384 + k) = o;
    }
}

extern "C" void kernel_launch(void* const* d_in, const int* in_sizes, int n_in,
                              void* d_out, int out_size, void* d_ws, size_t ws_size,
                              hipStream_t stream) {
    const float* x = (const float*)d_in[0];
    const float* adj = (const float*)d_in[1];
    const int* teams = (const int*)d_in[2];
    const int* slen = (const int*)d_in[3];
    const float* W1r = (const float*)d_in[4];
    const float* b1 = (const float*)d_in[5];
    const float* W1s = (const float*)d_in[6];
    const float* W2r = (const float*)d_in[7];
    const float* b2 = (const float*)d_in[8];
    const float* W2s = (const float*)d_in[9];
    const float* W3r = (const float*)d_in[10];
    const float* b3 = (const float*)d_in[11];
    const float* W3s = (const float*)d_in[12];
    const float* g1 = (const float*)d_in[13];
    const float* be1 = (const float*)d_in[14];
    const float* g2 = (const float*)d_in[15];
    const float* be2 = (const float*)d_in[16];
    const float* g3 = (const float*)d_in[17];
    const float* be3 = (const float*)d_in[18];
    const float* Wl = (const float*)d_in[19];
    const float* bl = (const float*)d_in[20];
    const float* att = (const float*)d_in[21];

    float* out = (float*)d_out;
    float* s_out = out;
    float* xcat = out + (size_t)NN * CC;
    float* oT = xcat + (size_t)NN * 384;
    float* oS = oT + (size_t)TT * 384;
    float* oR = oS + (size_t)TT * 384;

    char* ws = (char*)d_ws;
    size_t off = 0;
    int* nbr = (int*)(ws + off); off += (size_t)NN * CAP * 4;
    int* cnt = (int*)(ws + off); off += (size_t)NN * 4;
    u16* x0bf = (u16*)(ws + off); off += (size_t)(NN + 1) * CC * 2;
    u16* yp1 = (u16*)(ws + off); off += (size_t)(NN + 1) * CC * 2;
    u16* yp2 = (u16*)(ws + off); off += (size_t)(NN + 1) * CC * 2;
    u16* yp3 = (u16*)(ws + off); off += (size_t)(NN + 1) * CC * 2;
    u16* Abraw = (u16*)(ws + off); off += (size_t)NN * CC * 2;
    u16* wfrag = (u16*)(ws + off); off += (size_t)288 * 512 * 2;
    float* partials = (float*)(ws + off); off += (size_t)256 * 256 * 4;
    float* coefs = (float*)(ws + off); off += (size_t)4 * 256 * 4;  // [identity, c1, c2, c3]

    k_pre<<<3361, 256, 0, stream>>>(adj, W1r, W1s, W2r, W2s, W3r, W3s, Wl, x,
                                    nbr, cnt, wfrag, x0bf, yp1, yp2, yp3, coefs);
    // layer 1 (coef0 = identity)
    k_agg<<<2048, 256, 0, stream>>>(x0bf, nbr, cnt, Abraw, partials, g1, be1, coefs + 256);
    k_gemm<<<256, 256, 0, stream>>>(Abraw, x0bf, cnt, wfrag, b1, coefs, yp1, partials);
    // layer 2 (stats block finalizes coef1 inside agg)
    k_agg<<<2049, 256, 0, stream>>>(yp1, nbr, cnt, Abraw, partials, g1, be1, coefs + 256);
    k_gemm<<<256, 256, 0, stream>>>(Abraw, yp1, cnt, wfrag + 64 * 512, b2, coefs + 256, yp2, partials);
    // layer 3 (stats block finalizes coef2 inside agg)
    k_agg<<<2049, 256, 0, stream>>>(yp2, nbr, cnt, Abraw, partials, g2, be2, coefs + 512);
    k_gemm<<<256, 256, 0, stream>>>(Abraw, yp2, cnt, wfrag + 128 * 512, b3, coefs + 512, yp3, partials);
    // coef3, then outputs
    k_coef3<<<1, 256, 0, stream>>>(partials, g3, be3, coefs + 768);
    k_gfinal<<<256, 256, 0, stream>>>(yp1, yp2, yp3, coefs + 256,
                                      wfrag + 192 * 512, bl, s_out);
    k_tail<<<3584, 256, 0, stream>>>(yp1, yp2, yp3, coefs + 256, teams, slen, att,
                                     xcat, oT, oS, oR);
}

// Round 5
// 128.436 us; speedup vs baseline: 1.7692x; 1.0710x over previous
//
#include <hip/hip_runtime.h>
#include <stdint.h>

#define NN 8192
#define CC 128
#define TT 512
#define LL 30
#define CAP 64

typedef unsigned int uint32;
typedef unsigned short u16;

typedef float f32x4 __attribute__((ext_vector_type(4)));
typedef short bf16x8 __attribute__((ext_vector_type(8)));

__device__ __forceinline__ float bf2f(uint32 h) { return __uint_as_float(h << 16); }
__device__ __forceinline__ u16 f2bf(float f) {
    uint32 u = __float_as_uint(f);
    u = (u + 0x7fffu + ((u >> 16) & 1u)) >> 16;
    return (u16)u;
}
__device__ __forceinline__ uint32 pack2(float a, float b) {
    return (uint32)f2bf(a) | ((uint32)f2bf(b) << 16);
}

// ---- shared BN-stats finalize: partials[256][256] -> affine coef (1 block, 256 thr) ----
__device__ __forceinline__ void stats_reduce(const float* __restrict__ P,
                                             const float* __restrict__ g,
                                             const float* __restrict__ be,
                                             float* __restrict__ coefOut, int tid) {
    __shared__ float SS[256], QQ[256];
    int c = tid & 127, half = tid >> 7;
    float s = 0.f, q = 0.f;
    int b0 = half * 128;
#pragma unroll 8
    for (int b = b0; b < b0 + 128; ++b) {
        s += P[b * 256 + c];
        q += P[b * 256 + 128 + c];
    }
    SS[tid] = s; QQ[tid] = q;
    __syncthreads();
    if (tid < 128) {
        float sum = SS[tid] + SS[tid + 128];
        float sq = QQ[tid] + QQ[tid + 128];
        float mu = sum * (1.f / NN);
        float var = sq * (1.f / NN) - mu * mu;
        float rs = rsqrtf(var + 1e-5f);
        float a = g[tid] * rs;
        coefOut[tid] = a;
        coefOut[128 + tid] = be[tid] - mu * a;
    }
}

// ============ k_pre: adj scan + W frag pack + x0->bf16 + zero rows/identity coef ============
// blocks [0,2048): adj rows; [2048,2336): wfrag; [2336,3360): x0 convert; 3360: small init
__global__ __launch_bounds__(256) void k_pre(
    const float* __restrict__ adj,
    const float* __restrict__ W1r, const float* __restrict__ W1s,
    const float* __restrict__ W2r, const float* __restrict__ W2s,
    const float* __restrict__ W3r, const float* __restrict__ W3s,
    const float* __restrict__ Wl, const float* __restrict__ x0,
    int* __restrict__ nbr, int* __restrict__ cnt,
    u16* __restrict__ wfrag, u16* __restrict__ x0bf,
    u16* __restrict__ yp1, u16* __restrict__ yp2, u16* __restrict__ yp3,
    float* __restrict__ coefs) {
    int b = blockIdx.x, tid = threadIdx.x;
    if (b < 2048) {
        int row = b * 4 + (tid >> 6);
        int lane = tid & 63;
        const float4* arow = (const float4*)(adj + (size_t)row * NN);
        int base = 0;
        int* dst = nbr + (size_t)row * CAP;
        for (int it = 0; it < 32; ++it) {
            float4 v = arow[it * 64 + lane];
            float vv[4] = {v.x, v.y, v.z, v.w};
#pragma unroll
            for (int j = 0; j < 4; ++j) {
                unsigned long long m = __ballot(vv[j] != 0.f);
                if (vv[j] != 0.f) {
                    int pos = base + __popcll(m & ((1ull << lane) - 1ull));
                    if (pos < CAP) dst[pos] = it * 256 + lane * 4 + j;
                }
                base += __popcll(m);
            }
        }
        int nn = base < CAP ? base : CAP;
        int npad = (nn + 3) & ~3;
        for (int p = nn + lane; p < npad; p += 64) dst[p] = NN;  // sentinel -> zero row
        if (lane == 0) cnt[row] = nn;
    } else if (b < 2336) {
        int bb = b - 2048;
        const float* Wa;
        const float* Wb;
        int tile, gbase;
        if (bb < 64)       { Wa = W1r; Wb = W1s; tile = bb;       gbase = 0; }
        else if (bb < 128) { Wa = W2r; Wb = W2s; tile = bb - 64;  gbase = 64; }
        else if (bb < 192) { Wa = W3r; Wb = W3s; tile = bb - 128; gbase = 128; }
        else               { Wa = Wl;  Wb = nullptr; tile = bb - 192; gbase = 192; }
        int kt = tile >> 3, nt = tile & 7;
        int lane = tid & 63, i0 = (tid >> 6) * 2;
        int n = nt * 16 + (lane & 15);
        u16* dst = wfrag + ((size_t)(gbase + tile) * 64 + lane) * 8;
#pragma unroll
        for (int ii = 0; ii < 2; ++ii) {
            int i = i0 + ii;
            int k = kt * 32 + ((lane >> 4) * 8) + i;
            float v;
            if (Wb) v = (k < 128) ? Wa[k * CC + n] : Wb[(k - 128) * CC + n];
            else    v = Wa[k * CC + n];
            dst[i] = f2bf(v);
        }
    } else if (b < 3360) {
        int idx = (b - 2336) * 1024 + tid * 4;
        float4 v = *(const float4*)(x0 + idx);
        ushort4 o;
        o.x = f2bf(v.x); o.y = f2bf(v.y); o.z = f2bf(v.z); o.w = f2bf(v.w);
        *(ushort4*)(x0bf + idx) = o;
    } else {
        if (tid < 128) {
            x0bf[(size_t)NN * CC + tid] = 0;
            yp1[(size_t)NN * CC + tid] = 0;
            yp2[(size_t)NN * CC + tid] = 0;
            yp3[(size_t)NN * CC + tid] = 0;
            coefs[tid] = 1.f;        // layer-0 identity affine
            coefs[128 + tid] = 0.f;
        }
    }
}

// ============ k_agg: Abraw[row] = sum_nbr(src) (raw, bf16); block 2048 = prev-layer BN stats ============
__global__ __launch_bounds__(256) void k_agg(const u16* __restrict__ src,
                                             const int* __restrict__ nbr,
                                             const int* __restrict__ cnt,
                                             u16* __restrict__ Abraw,
                                             const float* __restrict__ P,
                                             const float* __restrict__ g,
                                             const float* __restrict__ be,
                                             float* __restrict__ coefOut) {
    if (blockIdx.x >= 2048) {  // hidden stats block (only launched for layers 2,3)
        stats_reduce(P, g, be, coefOut, threadIdx.x);
        return;
    }
    int row = blockIdx.x * 4 + (threadIdx.x >> 6);
    int lane = threadIdx.x & 63;
    int c = lane * 2;
    int nreal = cnt[row];
    int npad = (nreal + 3) & ~3;
    const int* nb = nbr + (size_t)row * CAP;
    float a0 = 0.f, a1 = 0.f;
    for (int j = 0; j < npad; j += 4) {
        int4 m = *(const int4*)(nb + j);
        uint32 v0 = *(const uint32*)(src + (size_t)m.x * CC + c);
        uint32 v1 = *(const uint32*)(src + (size_t)m.y * CC + c);
        uint32 v2 = *(const uint32*)(src + (size_t)m.z * CC + c);
        uint32 v3 = *(const uint32*)(src + (size_t)m.w * CC + c);
        a0 += bf2f(v0 & 0xffffu); a1 += bf2f(v0 >> 16);
        a0 += bf2f(v1 & 0xffffu); a1 += bf2f(v1 >> 16);
        a0 += bf2f(v2 & 0xffffu); a1 += bf2f(v2 >> 16);
        a0 += bf2f(v3 & 0xffffu); a1 += bf2f(v3 >> 16);
    }
    *(uint32*)(Abraw + (size_t)row * CC + c) = pack2(a0, a1);
}

// ============ k_gemm: stage A=[a*agg+b*n | a*y+b], yp = relu(A@[Wr;Ws]+bias), BN partials ============
// 512 threads (8 waves): wave w -> rows (w>>2)*16, cols (w&3)*32; 2 blocks-worth of waves per CU.
__global__ __launch_bounds__(512) void k_gemm(const u16* __restrict__ Abraw,
                                              const u16* __restrict__ yprev,
                                              const int* __restrict__ cnt,
                                              const u16* __restrict__ wfrag,
                                              const float* __restrict__ bias,
                                              const float* __restrict__ coefIn,
                                              u16* __restrict__ yp,
                                              float* __restrict__ partials) {
    __shared__ u16 A[32][264];  // +8 pad
    __shared__ float sSum[CC], sSq[CC];
    int tid = threadIdx.x, lane = tid & 63, wid = tid >> 6;
    int row0 = blockIdx.x * 32;
    if (tid < CC) { sSum[tid] = 0.f; sSq[tid] = 0.f; }
    for (int i = tid; i < 1024; i += 512) {
        int r = i >> 5, k = (i & 31) * 8;
        int row = row0 + r;
        uint4 raw;
        float fn;
        int c;
        if (k < 128) {
            c = k;
            raw = *(const uint4*)(Abraw + (size_t)row * CC + k);
            fn = (float)cnt[row];
        } else {
            c = k - 128;
            raw = *(const uint4*)(yprev + (size_t)row * CC + c);
            fn = 1.f;
        }
        float4 a0 = *(const float4*)(coefIn + c);
        float4 a1 = *(const float4*)(coefIn + c + 4);
        float4 b0 = *(const float4*)(coefIn + 128 + c);
        float4 b1 = *(const float4*)(coefIn + 128 + c + 4);
        uint4 o;
        o.x = pack2(a0.x * bf2f(raw.x & 0xffffu) + b0.x * fn, a0.y * bf2f(raw.x >> 16) + b0.y * fn);
        o.y = pack2(a0.z * bf2f(raw.y & 0xffffu) + b0.z * fn, a0.w * bf2f(raw.y >> 16) + b0.w * fn);
        o.z = pack2(a1.x * bf2f(raw.z & 0xffffu) + b1.x * fn, a1.y * bf2f(raw.z >> 16) + b1.y * fn);
        o.w = pack2(a1.z * bf2f(raw.w & 0xffffu) + b1.z * fn, a1.w * bf2f(raw.w >> 16) + b1.w * fn);
        *(uint4*)&A[r][k] = o;
    }
    __syncthreads();

    int mh = wid >> 2, nh = wid & 3;
    int arow = mh * 16 + (lane & 15);
    int kg = (lane >> 4) * 8;
    f32x4 acc[2];
#pragma unroll
    for (int nt = 0; nt < 2; ++nt) acc[nt] = (f32x4){0.f, 0.f, 0.f, 0.f};
#pragma unroll
    for (int kt = 0; kt < 8; ++kt) {
        bf16x8 a = *(const bf16x8*)&A[arow][kt * 32 + kg];
        const u16* wb = wfrag + ((size_t)(kt * 8 + nh * 2) * 64 + lane) * 8;
#pragma unroll
        for (int nt = 0; nt < 2; ++nt) {
            bf16x8 bfr = *(const bf16x8*)(wb + (size_t)nt * 512);
            acc[nt] = __builtin_amdgcn_mfma_f32_16x16x32_bf16(a, bfr, acc[nt], 0, 0, 0);
        }
    }
    int rowb = row0 + mh * 16 + ((lane >> 4) * 4);
#pragma unroll
    for (int nt = 0; nt < 2; ++nt) {
        int col = nh * 32 + nt * 16 + (lane & 15);
        float bv = bias[col];
        float s1 = 0.f, s2 = 0.f;
#pragma unroll
        for (int q = 0; q < 4; ++q) {
            float y = acc[nt][q] + bv;
            y = y > 0.f ? y : 0.f;
            yp[(size_t)(rowb + q) * CC + col] = f2bf(y);
            s1 += y;
            s2 += y * y;
        }
        s1 += __shfl_xor(s1, 16); s1 += __shfl_xor(s1, 32);
        s2 += __shfl_xor(s2, 16); s2 += __shfl_xor(s2, 32);
        if ((lane >> 4) == 0) { atomicAdd(&sSum[col], s1); atomicAdd(&sSq[col], s2); }
    }
    __syncthreads();
    if (tid < CC) {
        partials[(size_t)blockIdx.x * 256 + tid] = sSum[tid];
        partials[(size_t)blockIdx.x * 256 + CC + tid] = sSq[tid];
    }
}

// ============ k_coef3: finalize layer-3 BN coef (1 block) ============
__global__ __launch_bounds__(256) void k_coef3(const float* __restrict__ P,
                                               const float* __restrict__ g,
                                               const float* __restrict__ be,
                                               float* __restrict__ coefOut) {
    stats_reduce(P, g, be, coefOut, threadIdx.x);
}

// ============ k_out: s-GEMM [0,512) + team embeddings [512,1024) + xcat normalize [1024,4096) ============
__global__ __launch_bounds__(256) void k_out(
    const u16* __restrict__ yp1, const u16* __restrict__ yp2, const u16* __restrict__ yp3,
    const float* __restrict__ coefs,  // [3][256]
    const u16* __restrict__ wfrag, const float* __restrict__ bias,
    const int* __restrict__ teams, const int* __restrict__ slen_p,
    const float* __restrict__ att,
    float* __restrict__ sout, float* __restrict__ xcat,
    float* __restrict__ oT, float* __restrict__ oS, float* __restrict__ oR) {
    int b = blockIdx.x, tid = threadIdx.x;
    if (b < 512) {
        __shared__ u16 A[16][392];  // 384 + 8 pad (12.5 KB -> ~12 blocks/CU)
        int lane = tid & 63, wid = tid >> 6;
        int row0 = b * 16;
        for (int i = tid; i < 768; i += 256) {
            int r = i / 48, kk = (i % 48) * 8;
            int seg = kk >> 7, c = kk & 127;
            const u16* sp = (seg == 0 ? yp1 : seg == 1 ? yp2 : yp3) + (size_t)(row0 + r) * CC + c;
            uint4 raw = *(const uint4*)sp;
            const float* cf = coefs + seg * 256;
            float4 av0 = *(const float4*)(cf + c);
            float4 av1 = *(const float4*)(cf + c + 4);
            float4 bv0 = *(const float4*)(cf + 128 + c);
            float4 bv1 = *(const float4*)(cf + 128 + c + 4);
            uint4 o;
            o.x = pack2(av0.x * bf2f(raw.x & 0xffffu) + bv0.x, av0.y * bf2f(raw.x >> 16) + bv0.y);
            o.y = pack2(av0.z * bf2f(raw.y & 0xffffu) + bv0.z, av0.w * bf2f(raw.y >> 16) + bv0.w);
            o.z = pack2(av1.x * bf2f(raw.z & 0xffffu) + bv1.x, av1.y * bf2f(raw.z >> 16) + bv1.y);
            o.w = pack2(av1.z * bf2f(raw.w & 0xffffu) + bv1.z, av1.w * bf2f(raw.w >> 16) + bv1.w);
            *(uint4*)&A[r][kk] = o;
        }
        __syncthreads();
        int nh = wid;  // 0..3 -> 32-col group
        int arow = lane & 15;
        int kg = (lane >> 4) * 8;
        f32x4 acc[2];
#pragma unroll
        for (int nt = 0; nt < 2; ++nt) acc[nt] = (f32x4){0.f, 0.f, 0.f, 0.f};
#pragma unroll
        for (int kt = 0; kt < 12; ++kt) {
            bf16x8 a = *(const bf16x8*)&A[arow][kt * 32 + kg];
            const u16* wb = wfrag + ((size_t)(kt * 8 + nh * 2) * 64 + lane) * 8;
#pragma unroll
            for (int nt = 0; nt < 2; ++nt) {
                bf16x8 bfr = *(const bf16x8*)(wb + (size_t)nt * 512);
                acc[nt] = __builtin_amdgcn_mfma_f32_16x16x32_bf16(a, bfr, acc[nt], 0, 0, 0);
            }
        }
        int rowb = row0 + ((lane >> 4) * 4);
#pragma unroll
        for (int nt = 0; nt < 2; ++nt) {
            int col = nh * 32 + nt * 16 + (lane & 15);
            float bv = bias[col];
#pragma unroll
            for (int q = 0; q < 4; ++q) {
                float y = acc[nt][q] + bv;
                sout[(size_t)(rowb + q) * CC + col] = y > 0.f ? y : 0.f;
            }
        }
    } else if (b < 1024) {
        __shared__ float wT[LL], wS[LL], wR[LL];
        __shared__ int ids[LL];
        int t = b - 512;
        if (tid < 64) {
            int lane = tid;
            bool act = lane < LL;
            float a = act ? att[t * LL + lane] : 0.f;
            int id = act ? teams[t * LL + lane] : NN;
            if (act) ids[lane] = id;
            int sl = *slen_p;
            const float NEG = -1e30f;
            float v = act ? a : NEG;
#pragma unroll
            for (int o = 32; o > 0; o >>= 1) v = fmaxf(v, __shfl_xor(v, o));
            float mT = v;
            float eT = act ? __expf(a - mT) : 0.f;
            v = eT;
#pragma unroll
            for (int o = 32; o > 0; o >>= 1) v += __shfl_xor(v, o);
            float sT = v;
            bool inS = act && (lane < sl);
            v = inS ? a : NEG;
#pragma unroll
            for (int o = 32; o > 0; o >>= 1) v = fmaxf(v, __shfl_xor(v, o));
            float mS = v;
            float eS = inS ? __expf(a - mS) : 0.f;
            v = eS;
#pragma unroll
            for (int o = 32; o > 0; o >>= 1) v += __shfl_xor(v, o);
            float sS = v;
            bool inR = act && (lane >= sl) && (id != NN);
            v = inR ? a : NEG;
#pragma unroll
            for (int o = 32; o > 0; o >>= 1) v = fmaxf(v, __shfl_xor(v, o));
            float mR = v;
            float eR = inR ? __expf(a - mR) : 0.f;
            v = eR;
#pragma unroll
            for (int o = 32; o > 0; o >>= 1) v += __shfl_xor(v, o);
            float sR = v;
            if (act) {
                wT[lane] = eT / sT;
                wS[lane] = eS / sS;
                wR[lane] = eR / sR;
            }
        }
        __syncthreads();
        for (int d = tid; d < 384; d += 256) {
            int seg = d >> 7, c = d & 127;
            const u16* xb = seg == 0 ? yp1 : seg == 1 ? yp2 : yp3;
            float ca = coefs[seg * 256 + c];
            float cb = coefs[seg * 256 + 128 + c];
            float aT = 0.f, aS = 0.f, aR = 0.f;
            for (int l = 0; l < LL; ++l) {
                int id = ids[l];
                if (id < NN) {
                    float vv = ca * bf2f((uint32)xb[(size_t)id * CC + c]) + cb;
                    aT += wT[l] * vv;
                    aS += wS[l] * vv;
                    aR += wR[l] * vv;
                }
            }
            oT[(size_t)t * 384 + d] = aT;
            oS[(size_t)t * 384 + d] = aS;
            oR[(size_t)t * 384 + d] = aR;
        }
    } else {
        int idx = (b - 1024) * 256 + tid;  // one per 4 f32
        int n = idx / 96;
        int k = (idx % 96) * 4;
        int seg = k >> 7, c = k & 127;
        const u16* sp = (seg == 0 ? yp1 : seg == 1 ? yp2 : yp3) + (size_t)n * CC + c;
        ushort4 raw = *(const ushort4*)sp;
        const float* cf = coefs + seg * 256;
        float4 a = *(const float4*)(cf + c);
        float4 bb = *(const float4*)(cf + 128 + c);
        float4 o;
        o.x = a.x * bf2f((uint32)raw.x) + bb.x;
        o.y = a.y * bf2f((uint32)raw.y) + bb.y;
        o.z = a.z * bf2f((uint32)raw.z) + bb.z;
        o.w = a.w * bf2f((uint32)raw.w) + bb.w;
        *(float4*)(xcat + (size_t)n * 384 + k) = o;
    }
}

extern "C" void kernel_launch(void* const* d_in, const int* in_sizes, int n_in,
                              void* d_out, int out_size, void* d_ws, size_t ws_size,
                              hipStream_t stream) {
    const float* x = (const float*)d_in[0];
    const float* adj = (const float*)d_in[1];
    const int* teams = (const int*)d_in[2];
    const int* slen = (const int*)d_in[3];
    const float* W1r = (const float*)d_in[4];
    const float* b1 = (const float*)d_in[5];
    const float* W1s = (const float*)d_in[6];
    const float* W2r = (const float*)d_in[7];
    const float* b2 = (const float*)d_in[8];
    const float* W2s = (const float*)d_in[9];
    const float* W3r = (const float*)d_in[10];
    const float* b3 = (const float*)d_in[11];
    const float* W3s = (const float*)d_in[12];
    const float* g1 = (const float*)d_in[13];
    const float* be1 = (const float*)d_in[14];
    const float* g2 = (const float*)d_in[15];
    const float* be2 = (const float*)d_in[16];
    const float* g3 = (const float*)d_in[17];
    const float* be3 = (const float*)d_in[18];
    const float* Wl = (const float*)d_in[19];
    const float* bl = (const float*)d_in[20];
    const float* att = (const float*)d_in[21];

    float* out = (float*)d_out;
    float* s_out = out;
    float* xcat = out + (size_t)NN * CC;
    float* oT = xcat + (size_t)NN * 384;
    float* oS = oT + (size_t)TT * 384;
    float* oR = oS + (size_t)TT * 384;

    char* ws = (char*)d_ws;
    size_t off = 0;
    int* nbr = (int*)(ws + off); off += (size_t)NN * CAP * 4;
    int* cnt = (int*)(ws + off); off += (size_t)NN * 4;
    u16* x0bf = (u16*)(ws + off); off += (size_t)(NN + 1) * CC * 2;
    u16* yp1 = (u16*)(ws + off); off += (size_t)(NN + 1) * CC * 2;
    u16* yp2 = (u16*)(ws + off); off += (size_t)(NN + 1) * CC * 2;
    u16* yp3 = (u16*)(ws + off); off += (size_t)(NN + 1) * CC * 2;
    u16* Abraw = (u16*)(ws + off); off += (size_t)NN * CC * 2;
    u16* wfrag = (u16*)(ws + off); off += (size_t)288 * 512 * 2;
    float* partials = (float*)(ws + off); off += (size_t)256 * 256 * 4;
    float* coefs = (float*)(ws + off); off += (size_t)4 * 256 * 4;  // [identity, c1, c2, c3]

    k_pre<<<3361, 256, 0, stream>>>(adj, W1r, W1s, W2r, W2s, W3r, W3s, Wl, x,
                                    nbr, cnt, wfrag, x0bf, yp1, yp2, yp3, coefs);
    // layer 1 (coef0 = identity)
    k_agg<<<2048, 256, 0, stream>>>(x0bf, nbr, cnt, Abraw, partials, g1, be1, coefs + 256);
    k_gemm<<<256, 512, 0, stream>>>(Abraw, x0bf, cnt, wfrag, b1, coefs, yp1, partials);
    // layer 2 (stats block finalizes coef1 inside agg)
    k_agg<<<2049, 256, 0, stream>>>(yp1, nbr, cnt, Abraw, partials, g1, be1, coefs + 256);
    k_gemm<<<256, 512, 0, stream>>>(Abraw, yp1, cnt, wfrag + 64 * 512, b2, coefs + 256, yp2, partials);
    // layer 3 (stats block finalizes coef2 inside agg)
    k_agg<<<2049, 256, 0, stream>>>(yp2, nbr, cnt, Abraw, partials, g2, be2, coefs + 512);
    k_gemm<<<256, 512, 0, stream>>>(Abraw, yp2, cnt, wfrag + 128 * 512, b3, coefs + 512, yp3, partials);
    // coef3, then fused outputs
    k_coef3<<<1, 256, 0, stream>>>(partials, g3, be3, coefs + 768);
    k_out<<<4096, 256, 0, stream>>>(yp1, yp2, yp3, coefs + 256,
                                    wfrag + 192 * 512, bl, teams, slen, att,
                                    s_out, xcat, oT, oS, oR);
}